// Round 1
// baseline (486.925 us; speedup 1.0000x reference)
//
#include <hip/hip_runtime.h>
#include <stdint.h>

typedef _Float16 f16;
typedef _Float16 f16x8 __attribute__((ext_vector_type(8)));
typedef _Float16 f16x4 __attribute__((ext_vector_type(4)));
typedef float f32x4 __attribute__((ext_vector_type(4)));

#define GAS __attribute__((address_space(1)))
#define LAS __attribute__((address_space(3)))

// async global->LDS, 16 B per lane; LDS dest = wave-uniform base + lane*16
__device__ __forceinline__ void gl_lds16(const void* g, void* l) {
    __builtin_amdgcn_global_load_lds((const GAS uint32_t*)g, (LAS uint32_t*)l, 16, 0, 0);
}

__global__ __launch_bounds__(256) void zerof(float* __restrict__ p, int n) {
    int i = blockIdx.x * 256 + threadIdx.x;
    if (i < n) p[i] = 0.f;
}

__global__ __launch_bounds__(256) void cvt16(const float* __restrict__ in,
                                             f16* __restrict__ o, long n) {
    long i = (long)blockIdx.x * 256 + threadIdx.x;
    if (i < n) o[i] = (f16)in[i];
}

// w [27][Cin][Cout] fp32 -> wt [27][Cout][Cin] fp16 (B-fragment: 16B contiguous Cin)
__global__ __launch_bounds__(256) void wtrans16(const float* __restrict__ w,
                                                f16* __restrict__ wt,
                                                int Cin, int Cout) {
    long i = (long)blockIdx.x * 256 + threadIdx.x;
    long total = 27L * Cin * Cout;
    if (i >= total) return;
    int ci = (int)(i % Cin);
    long t = i / Cin;
    int co = (int)(t % Cout);
    int k  = (int)(t / Cout);
    wt[i] = (f16)w[((long)k * Cin + ci) * Cout + co];
}

// Dense implicit 3x3x3 conv, fully LDS-fed MFMA:
//  - A: 10y x 18x halo slab (128ch fp16 = 46080 B), double-buffered per z-stage,
//    DMA'd with global_load_lds (OOB sites -> zrow), XOR swizzle on source.
//  - B: per-tap weight panel [COUT][128ch] (32 KB / 8 KB), double-buffered per
//    TAP: iteration t issues DMA for tap t+1, computes tap t from LDS.
//  Block tile: 128 out rows = 8y x 16x of one out plane; 1 block/CU (157 KB LDS).
//  512 threads = 8 waves = 2 waves/SIMD (latency/issue overlap between barriers).
//  Waves: COUT=128 -> 4 row-groups x 2 col-halves, 32x64 tile each (RT=2,CT=4);
//         COUT=32  -> 8 row-groups, 16x32 tile each (RT=1,CT=2).
// LAYER 0: CIN=256 (2 halves, 1 in-plane, dz=1-p), COUT=128, grid 3*72
// LAYER 1: CIN=128, 3 in-planes, j=p+dz,   COUT=128, grid 3*72
// LAYER 2: CIN=128, 3 in-planes, j=p+dz-1, COUT=32,  grid 5*72
template <int LAYER>
__global__ __launch_bounds__(512, 2) void conv_dense(
    const f16* __restrict__ fin, const f16* __restrict__ wt,
    const f16* __restrict__ zrow, float* __restrict__ out,
    float* __restrict__ stats) {
    constexpr int COUT = (LAYER == 2) ? 32 : 128;
    constexpr int INRB = (LAYER == 0) ? 512 : 256;   // input row bytes
    constexpr int WRB  = (LAYER == 0) ? 512 : 256;   // weight row bytes per col
    constexpr int RT   = (COUT == 128) ? 2 : 1;      // 16-row tiles per wave
    constexpr int CT   = (COUT == 128) ? 4 : 2;      // 16-col tiles per wave
    constexpr int NBCH = COUT / 4;                   // B chunks (1 KB each)
    extern __shared__ char smem[];
    char* ldsA0 = smem;                 // 46080
    char* ldsA1 = smem + 46080;         // 46080
    char* ldsB0 = smem + 92160;         // COUT*256
    char* ldsB1 = smem + 92160 + COUT * 256;

    const int b = blockIdx.x;
    const int p = b / 72;               // out plane
    const int t0 = b % 72;
    const int y0 = (t0 / 6) * 8;
    const int x0 = (t0 % 6) * 16;
    const int tid = threadIdx.x;
    const int lane = tid & 63;
    const int wave = tid >> 6;          // 0..7
    const int q = lane >> 4;
    const int r16 = lane & 15;
    const int wr = ((COUT == 128) ? (wave >> 1) : wave) * (RT * 16);
    const int wc = ((COUT == 128) ? (wave & 1) : 0) * (CT * 16);

    // stage list (block-uniform): z-planes (and channel halves for LAYER 0)
    int S = 0;
    int js[3], dzs[3], hs[3];
    if (LAYER == 0) {
        js[0] = 0; dzs[0] = 1 - p; hs[0] = 0;
        js[1] = 0; dzs[1] = 1 - p; hs[1] = 1;
        S = 2;
    } else if (LAYER == 1) {
        for (int dz = -1; dz <= 1; dz++) {
            int j = p + dz;
            if (0 <= j && j < 3) { js[S] = j; dzs[S] = dz; hs[S] = 0; S++; }
        }
    } else {
        for (int dz = -1; dz <= 1; dz++) {
            int j = p + dz - 1;
            if (0 <= j && j < 3) { js[S] = j; dzs[S] = dz; hs[S] = 0; S++; }
        }
    }

    auto stageA = [&](int s, char* buf) {
        const int j = js[s], h = hs[s];
        const long pbase = (long)j * 9216;
        for (int ch = wave; ch < 45; ch += 8) {
            int site = ch * 4 + q;
            int sy = site / 18;
            int sx = site - sy * 18;
            int y = y0 - 1 + sy;
            int x = x0 - 1 + sx;
            int cc = r16 ^ (site & 7);
            bool ok = ((unsigned)y < 96u) & ((unsigned)x < 96u);
            const char* src = ok
                ? (const char*)fin + (pbase + y * 96 + x) * INRB + h * 256 + cc * 16
                : (const char*)zrow + cc * 16;
            gl_lds16(src, buf + ch * 1024);
        }
    };
    auto stageB = [&](int k, int h, char* buf) {
        for (int ch = wave; ch < NBCH; ch += 8) {
            int col = ch * 4 + q;
            int cc = r16 ^ (col & 7);
            const char* src = (const char*)wt + (long)(k * COUT + col) * WRB +
                              h * 256 + cc * 16;
            gl_lds16(src, buf + ch * 1024);
        }
    };

    f32x4 acc[RT][CT];
#pragma unroll
    for (int tr = 0; tr < RT; tr++)
#pragma unroll
        for (int c = 0; c < CT; c++) acc[tr][c] = f32x4{0.f, 0.f, 0.f, 0.f};

    stageA(0, ldsA0);
    stageB((dzs[0] + 1) * 9, hs[0], ldsB0);

    int tap = 0;
    for (int s = 0; s < S; s++) {
        const char* bufA = (s & 1) ? ldsA1 : ldsA0;
#pragma unroll
        for (int i = 0; i < 9; i++, tap++) {
            __syncthreads();   // drains DMA for tap `tap` (+A stage when due)
            if (i == 0 && s + 1 < S) stageA(s + 1, ((s + 1) & 1) ? ldsA1 : ldsA0);
            if (tap + 1 < S * 9) {
                int sn = (i == 8) ? s + 1 : s;
                int in2 = (i == 8) ? 0 : i + 1;
                stageB((dzs[sn] + 1) * 9 + in2, hs[sn], ((tap + 1) & 1) ? ldsB1 : ldsB0);
            }
            const char* bufB = (tap & 1) ? ldsB1 : ldsB0;
            const int dy = i / 3 - 1, dx = i % 3 - 1;
#pragma unroll
            for (int kk = 0; kk < 4; kk++) {
                f16x8 Af[RT], Bf[CT];
#pragma unroll
                for (int tr = 0; tr < RT; tr++) {
                    int site = (wr / 16 + tr + 1 + dy) * 18 + 1 + dx + r16;
                    Af[tr] = *(const f16x8*)(bufA + site * 256 +
                                             (((kk * 4 + q) ^ (site & 7)) << 4));
                }
#pragma unroll
                for (int c = 0; c < CT; c++) {
                    int col = wc + c * 16 + r16;
                    Bf[c] = *(const f16x8*)(bufB + col * 256 +
                                            (((kk * 4 + q) ^ (col & 7)) << 4));
                }
#pragma unroll
                for (int tr = 0; tr < RT; tr++)
#pragma unroll
                    for (int c = 0; c < CT; c++)
                        acc[tr][c] = __builtin_amdgcn_mfma_f32_16x16x32_f16(
                            Af[tr], Bf[c], acc[tr][c], 0, 0, 0);
            }
        }
    }
    // Epilogue: D row = q*4+reg within 16-row (x) tile; write + fused BN stats.
    const long mbase = (long)p * 9216 + (long)y0 * 96 + x0;
#pragma unroll
    for (int c = 0; c < CT; c++) {
        const int col = wc + c * 16 + r16;
        float sum = 0.f, ssq = 0.f;
#pragma unroll
        for (int tr = 0; tr < RT; tr++) {
            const int ly = wr / 16 + tr;
#pragma unroll
            for (int r = 0; r < 4; r++) {
                const int lx = q * 4 + r;
                float v = acc[tr][c][r];
                out[(mbase + ly * 96 + lx) * COUT + col] = v;
                sum += v;
                ssq = fmaf(v, v, ssq);
            }
        }
        sum += __shfl_xor(sum, 16);
        sum += __shfl_xor(sum, 32);
        ssq += __shfl_xor(ssq, 16);
        ssq += __shfl_xor(ssq, 32);
        if (q == 0) {
            atomicAdd(&stats[col], sum);
            atomicAdd(&stats[COUT + col], ssq);
        }
    }
}

// BN(train) + optional residual + ReLU, 4 elems/thread.
__global__ __launch_bounds__(256) void bn_apply4(
    const float4* __restrict__ f, const float* __restrict__ sums,
    const float* __restrict__ g, const float* __restrict__ bta,
    const f16x4* __restrict__ idn, f16* __restrict__ outh,
    float4* __restrict__ outf, long n4, int C, float invM) {
    long i = (long)blockIdx.x * 256 + threadIdx.x;
    if (i >= n4) return;
    int col0 = (int)((i * 4) & (C - 1));
    float4 v = f[i];
    float r[4] = {v.x, v.y, v.z, v.w};
    f16x4 id = {};
    if (idn) id = idn[i];
    f16x4 ho;
#pragma unroll
    for (int j = 0; j < 4; j++) {
        int c = col0 + j;
        float mu = sums[c] * invM;
        float var = sums[C + c] * invM - mu * mu;
        var = fmaxf(var, 0.f);
        float sc = g[c] * rsqrtf(var + 1e-5f);
        float x = (r[j] - mu) * sc + bta[c];
        if (idn) x += (float)id[j];
        x = fmaxf(x, 0.f);
        r[j] = x;
        ho[j] = (f16)x;
    }
    if (outf) outf[i] = make_float4(r[0], r[1], r[2], r[3]);
    else *(f16x4*)(outh + i * 4) = ho;
}

extern "C" void kernel_launch(void* const* d_in, const int* in_sizes, int n_in,
                              void* d_out, int out_size, void* d_ws, size_t ws_size,
                              hipStream_t stream) {
    (void)n_in; (void)out_size; (void)ws_size;
    const float* x    = (const float*)d_in[0];
    const float* w_s1 = (const float*)d_in[1];
    const float* g_s1 = (const float*)d_in[2];
    const float* b_s1 = (const float*)d_in[3];
    const float* w11  = (const float*)d_in[4];
    const float* g11  = (const float*)d_in[5];
    const float* b11  = (const float*)d_in[6];
    const float* w12  = (const float*)d_in[7];
    const float* g12  = (const float*)d_in[8];
    const float* b12  = (const float*)d_in[9];
    const float* w21  = (const float*)d_in[10];
    const float* g21  = (const float*)d_in[11];
    const float* b21  = (const float*)d_in[12];
    const float* w22  = (const float*)d_in[13];
    const float* g22  = (const float*)d_in[14];
    const float* b22  = (const float*)d_in[15];
    const float* w_s2 = (const float*)d_in[16];
    const float* g_s2 = (const float*)d_in[17];
    const float* b_s2 = (const float*)d_in[18];

    const int N0 = in_sizes[0] / 256;   // 9216
    const int M1 = in_sizes[19] / 27;   // 27648
    const int M2 = in_sizes[21] / 27;   // 46080

    char* base = (char*)d_ws;
    size_t off = 0;
    auto alloc = [&](size_t bytes) -> char* {
        off = (off + 255) & ~(size_t)255;
        char* p = base + off;
        off += bytes;
        return p;
    };
    f16* xh  = (f16*)alloc((size_t)N0 * 256 * 2);
    f16* w1  = (f16*)alloc(27UL * 128 * 256 * 2);
    f16* wa1 = (f16*)alloc(27UL * 128 * 128 * 2);
    f16* wa2 = (f16*)alloc(27UL * 128 * 128 * 2);
    f16* wb1 = (f16*)alloc(27UL * 128 * 128 * 2);
    f16* wb2 = (f16*)alloc(27UL * 128 * 128 * 2);
    f16* w2  = (f16*)alloc(27UL * 32 * 128 * 2);
    f16* fA  = (f16*)alloc((size_t)M1 * 128 * 2);
    f16* fB  = (f16*)alloc((size_t)M1 * 128 * 2);
    float* cbuf  = (float*)alloc((size_t)M1 * 128 * 4);  // covers M2*32 too
    float* stats = (float*)alloc(1344UL * 4);            // 5x256 + 64
    f16*   zrow  = (f16*)alloc(512);                     // zero site (256B used)

    // Enable >64KB dynamic LDS (host-side state; idempotent, capture-safe)
    const int lds01 = 92160 + 2 * 128 * 256;   // 157696
    const int lds2  = 92160 + 2 * 32 * 256;    // 108544
    (void)hipFuncSetAttribute((const void*)conv_dense<0>,
                              hipFuncAttributeMaxDynamicSharedMemorySize, lds01);
    (void)hipFuncSetAttribute((const void*)conv_dense<1>,
                              hipFuncAttributeMaxDynamicSharedMemorySize, lds01);
    (void)hipFuncSetAttribute((const void*)conv_dense<2>,
                              hipFuncAttributeMaxDynamicSharedMemorySize, lds2);

    // stats (5376 B) + zrow (512 B) contiguous -> zero 1472 floats
    zerof<<<6, 256, 0, stream>>>(stats, 1472);

    long nx = (long)N0 * 256;
    cvt16<<<(int)((nx + 255) / 256), 256, 0, stream>>>(x, xh, nx);
    wtrans16<<<(27 * 256 * 128 + 255) / 256, 256, 0, stream>>>(w_s1, w1, 256, 128);
    wtrans16<<<(27 * 128 * 128 + 255) / 256, 256, 0, stream>>>(w11, wa1, 128, 128);
    wtrans16<<<(27 * 128 * 128 + 255) / 256, 256, 0, stream>>>(w12, wa2, 128, 128);
    wtrans16<<<(27 * 128 * 128 + 255) / 256, 256, 0, stream>>>(w21, wb1, 128, 128);
    wtrans16<<<(27 * 128 * 128 + 255) / 256, 256, 0, stream>>>(w22, wb2, 128, 128);
    wtrans16<<<(27 * 128 * 32 + 255) / 256, 256, 0, stream>>>(w_s2, w2, 128, 32);

    const float inv1 = 1.f / (float)M1, inv2 = 1.f / (float)M2;
    const int g1 = 3 * 72;              // 216 blocks (128 rows each)
    const int g2 = 5 * 72;              // 360 blocks
    const long n4a = (long)M1 * 128 / 4;
    const long n4b = (long)M2 * 32 / 4;
    const int ga = (int)((n4a + 255) / 256);
    const int gb = (int)((n4b + 255) / 256);

    // L1: spconv1 (256 -> 128)
    conv_dense<0><<<g1, 512, lds01, stream>>>(xh, w1, zrow, cbuf, stats);
    bn_apply4<<<ga, 256, 0, stream>>>((float4*)cbuf, stats, g_s1, b_s1,
                                      nullptr, fA, nullptr, n4a, 128, inv1);
    // Block 1
    conv_dense<1><<<g1, 512, lds01, stream>>>(fA, wa1, zrow, cbuf, stats + 256);
    bn_apply4<<<ga, 256, 0, stream>>>((float4*)cbuf, stats + 256, g11, b11,
                                      nullptr, fB, nullptr, n4a, 128, inv1);
    conv_dense<1><<<g1, 512, lds01, stream>>>(fB, wa2, zrow, cbuf, stats + 512);
    bn_apply4<<<ga, 256, 0, stream>>>((float4*)cbuf, stats + 512, g12, b12,
                                      (const f16x4*)fA, fA, nullptr, n4a, 128, inv1);
    // Block 2
    conv_dense<1><<<g1, 512, lds01, stream>>>(fA, wb1, zrow, cbuf, stats + 768);
    bn_apply4<<<ga, 256, 0, stream>>>((float4*)cbuf, stats + 768, g21, b21,
                                      nullptr, fB, nullptr, n4a, 128, inv1);
    conv_dense<1><<<g1, 512, lds01, stream>>>(fB, wb2, zrow, cbuf, stats + 1024);
    bn_apply4<<<ga, 256, 0, stream>>>((float4*)cbuf, stats + 1024, g22, b22,
                                      (const f16x4*)fA, fA, nullptr, n4a, 128, inv1);
    // L6: spconv2 (128 -> 32), final fp32 output
    conv_dense<2><<<g2, 512, lds2, stream>>>(fA, w2, zrow, cbuf, stats + 1280);
    bn_apply4<<<gb, 256, 0, stream>>>((float4*)cbuf, stats + 1280, g_s2, b_s2,
                                      nullptr, nullptr, (float4*)d_out, n4b, 32, inv2);
}

// Round 2
// 405.779 us; speedup vs baseline: 1.2000x; 1.2000x over previous
//
#include <hip/hip_runtime.h>
#include <stdint.h>

typedef _Float16 f16;
typedef _Float16 f16x8 __attribute__((ext_vector_type(8)));
typedef _Float16 f16x4 __attribute__((ext_vector_type(4)));
typedef float f32x4 __attribute__((ext_vector_type(4)));

#define GAS __attribute__((address_space(1)))
#define LAS __attribute__((address_space(3)))

// async global->LDS, 16 B per lane; LDS dest = wave-uniform base + lane*16
__device__ __forceinline__ void gl_lds16(const void* g, void* l) {
    __builtin_amdgcn_global_load_lds((const GAS uint32_t*)g, (LAS uint32_t*)l, 16, 0, 0);
}

__global__ __launch_bounds__(256) void zerof(float* __restrict__ p, int n) {
    int i = blockIdx.x * 256 + threadIdx.x;
    if (i < n) p[i] = 0.f;
}

__global__ __launch_bounds__(256) void cvt16(const float* __restrict__ in,
                                             f16* __restrict__ o, long n) {
    long i = (long)blockIdx.x * 256 + threadIdx.x;
    if (i < n) o[i] = (f16)in[i];
}

// w [27][Cin][Cout] fp32 -> wt [27][Cout][Cin] fp16 (B-fragment: 16B contiguous Cin)
__global__ __launch_bounds__(256) void wtrans16(const float* __restrict__ w,
                                                f16* __restrict__ wt,
                                                int Cin, int Cout) {
    long i = (long)blockIdx.x * 256 + threadIdx.x;
    long total = 27L * Cin * Cout;
    if (i >= total) return;
    int ci = (int)(i % Cin);
    long t = i / Cin;
    int co = (int)(t % Cout);
    int k  = (int)(t / Cout);
    wt[i] = (f16)w[((long)k * Cin + ci) * Cout + co];
}

// Dense implicit 3x3x3 conv, fully LDS-fed MFMA:
//  - A: 10y x 18x halo slab (128ch fp16 = 46080 B), double-buffered per z-stage,
//    DMA'd with global_load_lds (OOB sites -> zrow), XOR swizzle on source.
//  - B: per-tap weight panel [COUT][128ch] (32 KB / 8 KB), double-buffered per
//    TAP: iteration t issues DMA for tap t+1, computes tap t from LDS.
//  Block tile: 128 out rows = 8y x 16x of one out plane; 1 block/CU (157 KB LDS).
//  512 threads = 8 waves = 2 waves/SIMD, with K-SPLIT so per-wave reuse stays at
//  round-0 level: 8 waves = (pair group) x (K-half kh). Each wave computes the
//  full pair tile over HALF of K (kk in {2kh, 2kh+1}); LDS traffic/tap/CU is
//  identical to the 4-wave config (each frag read by exactly 2 waves), but with
//  2 waves/SIMD hiding ds_read latency + barrier drain. K-halves are summed via
//  a one-shot LDS exchange in the B buffers (dead after the last tap; the pair
//  regions exactly fill 2*COUT*256 B).
//  Pairs: COUT=128 -> 4 pairs = 2 row-groups x 2 col-halves, 64x64 tile each;
//         COUT=32  -> 4 pairs = 4 row-groups, 32x32 tile each.
// LAYER 0: CIN=256 (2 halves, 1 in-plane, dz=1-p), COUT=128, grid 3*72
// LAYER 1: CIN=128, 3 in-planes, j=p+dz,   COUT=128, grid 3*72
// LAYER 2: CIN=128, 3 in-planes, j=p+dz-1, COUT=32,  grid 5*72
template <int LAYER>
__global__ __launch_bounds__(512, 2) void conv_dense(
    const f16* __restrict__ fin, const f16* __restrict__ wt,
    const f16* __restrict__ zrow, float* __restrict__ out,
    float* __restrict__ stats) {
    constexpr int COUT = (LAYER == 2) ? 32 : 128;
    constexpr int INRB = (LAYER == 0) ? 512 : 256;   // input row bytes
    constexpr int WRB  = (LAYER == 0) ? 512 : 256;   // weight row bytes per col
    constexpr int RT   = (COUT == 128) ? 4 : 2;      // 16-row tiles per wave
    constexpr int CT   = (COUT == 128) ? 4 : 2;      // 16-col tiles per wave
    constexpr int NBCH = COUT / 4;                   // B chunks (1 KB each)
    extern __shared__ char smem[];
    char* ldsA0 = smem;                 // 46080
    char* ldsA1 = smem + 46080;         // 46080
    char* ldsB0 = smem + 92160;         // COUT*256
    char* ldsB1 = smem + 92160 + COUT * 256;

    const int b = blockIdx.x;
    const int p = b / 72;               // out plane
    const int t0 = b % 72;
    const int y0 = (t0 / 6) * 8;
    const int x0 = (t0 % 6) * 16;
    const int tid = threadIdx.x;
    const int lane = tid & 63;
    const int wave = tid >> 6;          // 0..7
    const int kh = wave & 1;            // K-half: kk in {2kh, 2kh+1}
    const int pairId = wave >> 1;       // 0..3 output-tile group
    const int q = lane >> 4;
    const int r16 = lane & 15;
    const int wr = ((COUT == 128) ? (pairId >> 1) : pairId) * (RT * 16);
    const int wc = ((COUT == 128) ? (pairId & 1) : 0) * (CT * 16);

    // stage list (block-uniform): z-planes (and channel halves for LAYER 0)
    int S = 0;
    int js[3], dzs[3], hs[3];
    if (LAYER == 0) {
        js[0] = 0; dzs[0] = 1 - p; hs[0] = 0;
        js[1] = 0; dzs[1] = 1 - p; hs[1] = 1;
        S = 2;
    } else if (LAYER == 1) {
        for (int dz = -1; dz <= 1; dz++) {
            int j = p + dz;
            if (0 <= j && j < 3) { js[S] = j; dzs[S] = dz; hs[S] = 0; S++; }
        }
    } else {
        for (int dz = -1; dz <= 1; dz++) {
            int j = p + dz - 1;
            if (0 <= j && j < 3) { js[S] = j; dzs[S] = dz; hs[S] = 0; S++; }
        }
    }

    auto stageA = [&](int s, char* buf) {
        const int j = js[s], h = hs[s];
        const long pbase = (long)j * 9216;
        for (int ch = wave; ch < 45; ch += 8) {
            int site = ch * 4 + q;
            int sy = site / 18;
            int sx = site - sy * 18;
            int y = y0 - 1 + sy;
            int x = x0 - 1 + sx;
            int cc = r16 ^ (site & 7);
            bool ok = ((unsigned)y < 96u) & ((unsigned)x < 96u);
            const char* src = ok
                ? (const char*)fin + (pbase + y * 96 + x) * INRB + h * 256 + cc * 16
                : (const char*)zrow + cc * 16;
            gl_lds16(src, buf + ch * 1024);
        }
    };
    auto stageB = [&](int k, int h, char* buf) {
        for (int ch = wave; ch < NBCH; ch += 8) {
            int col = ch * 4 + q;
            int cc = r16 ^ (col & 7);
            const char* src = (const char*)wt + (long)(k * COUT + col) * WRB +
                              h * 256 + cc * 16;
            gl_lds16(src, buf + ch * 1024);
        }
    };

    f32x4 acc[RT][CT];
#pragma unroll
    for (int tr = 0; tr < RT; tr++)
#pragma unroll
        for (int c = 0; c < CT; c++) acc[tr][c] = f32x4{0.f, 0.f, 0.f, 0.f};

    stageA(0, ldsA0);
    stageB((dzs[0] + 1) * 9, hs[0], ldsB0);

    int tap = 0;
    for (int s = 0; s < S; s++) {
        const char* bufA = (s & 1) ? ldsA1 : ldsA0;
#pragma unroll
        for (int i = 0; i < 9; i++, tap++) {
            __syncthreads();   // drains DMA for tap `tap` (+A stage when due)
            if (i == 0 && s + 1 < S) stageA(s + 1, ((s + 1) & 1) ? ldsA1 : ldsA0);
            if (tap + 1 < S * 9) {
                int sn = (i == 8) ? s + 1 : s;
                int in2 = (i == 8) ? 0 : i + 1;
                stageB((dzs[sn] + 1) * 9 + in2, hs[sn], ((tap + 1) & 1) ? ldsB1 : ldsB0);
            }
            const char* bufB = (tap & 1) ? ldsB1 : ldsB0;
            const int dy = i / 3 - 1, dx = i % 3 - 1;
#pragma unroll
            for (int kk2 = 0; kk2 < 2; kk2++) {
                const int kk = kh * 2 + kk2;   // this wave's K-half chunk
                f16x8 Af[RT], Bf[CT];
#pragma unroll
                for (int tr = 0; tr < RT; tr++) {
                    int site = (wr / 16 + tr + 1 + dy) * 18 + 1 + dx + r16;
                    Af[tr] = *(const f16x8*)(bufA + site * 256 +
                                             (((kk * 4 + q) ^ (site & 7)) << 4));
                }
#pragma unroll
                for (int c = 0; c < CT; c++) {
                    int col = wc + c * 16 + r16;
                    Bf[c] = *(const f16x8*)(bufB + col * 256 +
                                            (((kk * 4 + q) ^ (col & 7)) << 4));
                }
#pragma unroll
                for (int tr = 0; tr < RT; tr++)
#pragma unroll
                    for (int c = 0; c < CT; c++)
                        acc[tr][c] = __builtin_amdgcn_mfma_f32_16x16x32_f16(
                            Af[tr], Bf[c], acc[tr][c], 0, 0, 0);
            }
        }
    }

    // K-half reduction: kh=1 waves park partials in the (now dead) B buffers,
    // kh=0 waves add them. Layout lane-contiguous 1 KB chunks (conflict-free).
    char* xch = smem + 92160;                       // 2*COUT*256 B total
    constexpr int XR = RT * CT * 1024;              // bytes per pair region
    __syncthreads();                                 // all tap reads of ldsB done
    if (kh == 1) {
#pragma unroll
        for (int tr = 0; tr < RT; tr++)
#pragma unroll
            for (int c = 0; c < CT; c++)
                *(f32x4*)(xch + pairId * XR + (tr * CT + c) * 1024 + lane * 16) =
                    acc[tr][c];
    }
    __syncthreads();
    if (kh == 1) return;                             // no barriers past this point
#pragma unroll
    for (int tr = 0; tr < RT; tr++)
#pragma unroll
        for (int c = 0; c < CT; c++)
            acc[tr][c] += *(const f32x4*)(xch + pairId * XR + (tr * CT + c) * 1024 +
                                          lane * 16);

    // Epilogue: D row = q*4+reg within 16-row (x) tile; write + fused BN stats.
    const long mbase = (long)p * 9216 + (long)y0 * 96 + x0;
#pragma unroll
    for (int c = 0; c < CT; c++) {
        const int col = wc + c * 16 + r16;
        float sum = 0.f, ssq = 0.f;
#pragma unroll
        for (int tr = 0; tr < RT; tr++) {
            const int ly = wr / 16 + tr;
#pragma unroll
            for (int r = 0; r < 4; r++) {
                const int lx = q * 4 + r;
                float v = acc[tr][c][r];
                out[(mbase + ly * 96 + lx) * COUT + col] = v;
                sum += v;
                ssq = fmaf(v, v, ssq);
            }
        }
        sum += __shfl_xor(sum, 16);
        sum += __shfl_xor(sum, 32);
        ssq += __shfl_xor(ssq, 16);
        ssq += __shfl_xor(ssq, 32);
        if (q == 0) {
            atomicAdd(&stats[col], sum);
            atomicAdd(&stats[COUT + col], ssq);
        }
    }
}

// BN(train) + optional residual + ReLU, 4 elems/thread.
__global__ __launch_bounds__(256) void bn_apply4(
    const float4* __restrict__ f, const float* __restrict__ sums,
    const float* __restrict__ g, const float* __restrict__ bta,
    const f16x4* __restrict__ idn, f16* __restrict__ outh,
    float4* __restrict__ outf, long n4, int C, float invM) {
    long i = (long)blockIdx.x * 256 + threadIdx.x;
    if (i >= n4) return;
    int col0 = (int)((i * 4) & (C - 1));
    float4 v = f[i];
    float r[4] = {v.x, v.y, v.z, v.w};
    f16x4 id = {};
    if (idn) id = idn[i];
    f16x4 ho;
#pragma unroll
    for (int j = 0; j < 4; j++) {
        int c = col0 + j;
        float mu = sums[c] * invM;
        float var = sums[C + c] * invM - mu * mu;
        var = fmaxf(var, 0.f);
        float sc = g[c] * rsqrtf(var + 1e-5f);
        float x = (r[j] - mu) * sc + bta[c];
        if (idn) x += (float)id[j];
        x = fmaxf(x, 0.f);
        r[j] = x;
        ho[j] = (f16)x;
    }
    if (outf) outf[i] = make_float4(r[0], r[1], r[2], r[3]);
    else *(f16x4*)(outh + i * 4) = ho;
}

extern "C" void kernel_launch(void* const* d_in, const int* in_sizes, int n_in,
                              void* d_out, int out_size, void* d_ws, size_t ws_size,
                              hipStream_t stream) {
    (void)n_in; (void)out_size; (void)ws_size;
    const float* x    = (const float*)d_in[0];
    const float* w_s1 = (const float*)d_in[1];
    const float* g_s1 = (const float*)d_in[2];
    const float* b_s1 = (const float*)d_in[3];
    const float* w11  = (const float*)d_in[4];
    const float* g11  = (const float*)d_in[5];
    const float* b11  = (const float*)d_in[6];
    const float* w12  = (const float*)d_in[7];
    const float* g12  = (const float*)d_in[8];
    const float* b12  = (const float*)d_in[9];
    const float* w21  = (const float*)d_in[10];
    const float* g21  = (const float*)d_in[11];
    const float* b21  = (const float*)d_in[12];
    const float* w22  = (const float*)d_in[13];
    const float* g22  = (const float*)d_in[14];
    const float* b22  = (const float*)d_in[15];
    const float* w_s2 = (const float*)d_in[16];
    const float* g_s2 = (const float*)d_in[17];
    const float* b_s2 = (const float*)d_in[18];

    const int N0 = in_sizes[0] / 256;   // 9216
    const int M1 = in_sizes[19] / 27;   // 27648
    const int M2 = in_sizes[21] / 27;   // 46080

    char* base = (char*)d_ws;
    size_t off = 0;
    auto alloc = [&](size_t bytes) -> char* {
        off = (off + 255) & ~(size_t)255;
        char* p = base + off;
        off += bytes;
        return p;
    };
    f16* xh  = (f16*)alloc((size_t)N0 * 256 * 2);
    f16* w1  = (f16*)alloc(27UL * 128 * 256 * 2);
    f16* wa1 = (f16*)alloc(27UL * 128 * 128 * 2);
    f16* wa2 = (f16*)alloc(27UL * 128 * 128 * 2);
    f16* wb1 = (f16*)alloc(27UL * 128 * 128 * 2);
    f16* wb2 = (f16*)alloc(27UL * 128 * 128 * 2);
    f16* w2  = (f16*)alloc(27UL * 32 * 128 * 2);
    f16* fA  = (f16*)alloc((size_t)M1 * 128 * 2);
    f16* fB  = (f16*)alloc((size_t)M1 * 128 * 2);
    float* cbuf  = (float*)alloc((size_t)M1 * 128 * 4);  // covers M2*32 too
    float* stats = (float*)alloc(1344UL * 4);            // 5x256 + 64
    f16*   zrow  = (f16*)alloc(512);                     // zero site (256B used)

    // Enable >64KB dynamic LDS (host-side state; idempotent, capture-safe)
    const int lds01 = 92160 + 2 * 128 * 256;   // 157696
    const int lds2  = 92160 + 2 * 32 * 256;    // 108544
    (void)hipFuncSetAttribute((const void*)conv_dense<0>,
                              hipFuncAttributeMaxDynamicSharedMemorySize, lds01);
    (void)hipFuncSetAttribute((const void*)conv_dense<1>,
                              hipFuncAttributeMaxDynamicSharedMemorySize, lds01);
    (void)hipFuncSetAttribute((const void*)conv_dense<2>,
                              hipFuncAttributeMaxDynamicSharedMemorySize, lds2);

    // stats (5376 B) + zrow (512 B) contiguous -> zero 1472 floats
    zerof<<<6, 256, 0, stream>>>(stats, 1472);

    long nx = (long)N0 * 256;
    cvt16<<<(int)((nx + 255) / 256), 256, 0, stream>>>(x, xh, nx);
    wtrans16<<<(27 * 256 * 128 + 255) / 256, 256, 0, stream>>>(w_s1, w1, 256, 128);
    wtrans16<<<(27 * 128 * 128 + 255) / 256, 256, 0, stream>>>(w11, wa1, 128, 128);
    wtrans16<<<(27 * 128 * 128 + 255) / 256, 256, 0, stream>>>(w12, wa2, 128, 128);
    wtrans16<<<(27 * 128 * 128 + 255) / 256, 256, 0, stream>>>(w21, wb1, 128, 128);
    wtrans16<<<(27 * 128 * 128 + 255) / 256, 256, 0, stream>>>(w22, wb2, 128, 128);
    wtrans16<<<(27 * 128 * 32 + 255) / 256, 256, 0, stream>>>(w_s2, w2, 128, 32);

    const float inv1 = 1.f / (float)M1, inv2 = 1.f / (float)M2;
    const int g1 = 3 * 72;              // 216 blocks (128 rows each)
    const int g2 = 5 * 72;              // 360 blocks
    const long n4a = (long)M1 * 128 / 4;
    const long n4b = (long)M2 * 32 / 4;
    const int ga = (int)((n4a + 255) / 256);
    const int gb = (int)((n4b + 255) / 256);

    // L1: spconv1 (256 -> 128)
    conv_dense<0><<<g1, 512, lds01, stream>>>(xh, w1, zrow, cbuf, stats);
    bn_apply4<<<ga, 256, 0, stream>>>((float4*)cbuf, stats, g_s1, b_s1,
                                      nullptr, fA, nullptr, n4a, 128, inv1);
    // Block 1
    conv_dense<1><<<g1, 512, lds01, stream>>>(fA, wa1, zrow, cbuf, stats + 256);
    bn_apply4<<<ga, 256, 0, stream>>>((float4*)cbuf, stats + 256, g11, b11,
                                      nullptr, fB, nullptr, n4a, 128, inv1);
    conv_dense<1><<<g1, 512, lds01, stream>>>(fB, wa2, zrow, cbuf, stats + 512);
    bn_apply4<<<ga, 256, 0, stream>>>((float4*)cbuf, stats + 512, g12, b12,
                                      (const f16x4*)fA, fA, nullptr, n4a, 128, inv1);
    // Block 2
    conv_dense<1><<<g1, 512, lds01, stream>>>(fA, wb1, zrow, cbuf, stats + 768);
    bn_apply4<<<ga, 256, 0, stream>>>((float4*)cbuf, stats + 768, g21, b21,
                                      nullptr, fB, nullptr, n4a, 128, inv1);
    conv_dense<1><<<g1, 512, lds01, stream>>>(fB, wb2, zrow, cbuf, stats + 1024);
    bn_apply4<<<ga, 256, 0, stream>>>((float4*)cbuf, stats + 1024, g22, b22,
                                      (const f16x4*)fA, fA, nullptr, n4a, 128, inv1);
    // L6: spconv2 (128 -> 32), final fp32 output
    conv_dense<2><<<g2, 512, lds2, stream>>>(fA, w2, zrow, cbuf, stats + 1280);
    bn_apply4<<<gb, 256, 0, stream>>>((float4*)cbuf, stats + 1280, g_s2, b_s2,
                                      nullptr, nullptr, (float4*)d_out, n4b, 32, inv2);
}